// Round 3
// baseline (182.847 us; speedup 1.0000x reference)
//
#include <hip/hip_runtime.h>

struct F4 { float x, y, z, w; };  // 4B-aligned quad store

__global__ __launch_bounds__(256) void GraphProjection_57483842289710_kernel(
    const float* __restrict__ coord,
    const float* __restrict__ f56,
    const float* __restrict__ f28,
    const float* __restrict__ f14,
    const float* __restrict__ f7,
    float* __restrict__ out,
    int n)
{
    const int t = threadIdx.x;

    // ---- loop-invariant per-thread level params (selected ONCE; the point
    // loop below is branch-free for the gather waves) ----
    const int ch = 4 * t;                 // channels ch..ch+3 of the 960
    const float* f; int C, H; float inv; int c;
    if (ch < 64)       { f = f56; C = 64;  H = 56; inv = 0.25f;    c = ch;       }
    else if (ch < 192) { f = f28; C = 128; H = 28; inv = 0.125f;   c = ch - 64;  }
    else if (ch < 448) { f = f14; C = 256; H = 14; inv = 0.0625f;  c = ch - 192; }
    else               { f = f7;  C = 512; H = 7;  inv = 0.03125f; c = ch - 448; }
    const float* __restrict__ fc = f + c; // 16B-aligned per-thread base
    const float Hm1 = (float)(H - 1);     // (unused float clamp removed; int clamp below)

    #pragma unroll 2
    for (int p = blockIdx.x; p < n; p += gridDim.x) {
        float* __restrict__ orow = out + (size_t)p * 963;

        const float X = coord[p * 3 + 0];
        const float Y = coord[p * 3 + 1];
        const float Z = coord[p * 3 + 2];

        // one IEEE divide shared by h and w (<=2ulp vs ref's two divides;
        // bilinear output is continuous in h,w so the diff stays ~1e-5)
        const float rz = 1.0f / (-Z);
        float h = 250.0f * (-Y) * rz + 112.0f;
        float w = 250.0f * X  * rz + 112.0f;
        h = fminf(fmaxf(h, 0.0f), 223.0f);
        w = fminf(fmaxf(w, 0.0f), 223.0f);

        if (t < 240) {
            const float x = h * inv, y = w * inv;
            const float x1 = floorf(x), x2 = ceilf(x);
            const float y1 = floorf(y), y2 = ceilf(y);
            const int xi1 = min(max((int)x1, 0), H - 1);
            const int xi2 = min(max((int)x2, 0), H - 1);
            const int yi1 = min(max((int)y1, 0), H - 1);
            const int yi2 = min(max((int)y2, 0), H - 1);
            const float w11 = (x2 - x) * (y2 - y);
            const float w21 = (x - x1) * (y2 - y);
            const float w12 = (x2 - x) * (y - y1);
            const float w22 = (x - x1) * (y - y1);

            const int r1 = xi1 * H, r2 = xi2 * H;
            const float4 a = *reinterpret_cast<const float4*>(fc + (r1 + yi1) * C);
            const float4 b = *reinterpret_cast<const float4*>(fc + (r2 + yi1) * C);
            const float4 d = *reinterpret_cast<const float4*>(fc + (r1 + yi2) * C);
            const float4 e = *reinterpret_cast<const float4*>(fc + (r2 + yi2) * C);

            F4 r;
            r.x = w11 * a.x + w21 * b.x + w12 * d.x + w22 * e.x;
            r.y = w11 * a.y + w21 * b.y + w12 * d.y + w22 * e.y;
            r.z = w11 * a.z + w21 * b.z + w12 * d.z + w22 * e.z;
            r.w = w11 * a.w + w21 * b.w + w12 * d.w + w22 * e.w;
            *reinterpret_cast<F4*>(orow + 3 + ch) = r;
        } else if (t < 243) {
            orow[t - 240] = coord[p * 3 + (t - 240)];
        }
        (void)Hm1;
    }
}

extern "C" void kernel_launch(void* const* d_in, const int* in_sizes, int n_in,
                              void* d_out, int out_size, void* d_ws, size_t ws_size,
                              hipStream_t stream) {
    const float* coord = (const float*)d_in[0];
    const float* f56   = (const float*)d_in[1];
    const float* f28   = (const float*)d_in[2];
    const float* f14   = (const float*)d_in[3];
    const float* f7    = (const float*)d_in[4];
    float* out = (float*)d_out;

    int n = in_sizes[0] / 3;  // 131072 points
    int grid = n < 2048 ? n : 2048;  // 8 blocks/CU resident; 64 points each
    GraphProjection_57483842289710_kernel<<<grid, 256, 0, stream>>>(
        coord, f56, f28, f14, f7, out, n);
}

// Round 4
// 150.947 us; speedup vs baseline: 1.2113x; 1.2113x over previous
//
#include <hip/hip_runtime.h>

struct F4 { float x, y, z, w; };  // 4B-aligned quad store

constexpr int PPB = 16;  // consecutive points per block: sequential 61KB store
                         // stream per block, 8192 blocks (kills dispatch floor)

__global__ __launch_bounds__(256) void GraphProjection_57483842289710_kernel(
    const float* __restrict__ coord,
    const float* __restrict__ f56,
    const float* __restrict__ f28,
    const float* __restrict__ f14,
    const float* __restrict__ f7,
    float* __restrict__ out,
    int n)
{
    const int t = threadIdx.x;

    // ---- loop-invariant per-thread level params (selected ONCE) ----
    const int ch = 4 * t;                 // channels ch..ch+3 of the 960
    const float* f; int C, H; float inv;
    if (ch < 64)       { f = f56 + ch;        C = 64;  H = 56; inv = 0.25f;    }
    else if (ch < 192) { f = f28 + (ch - 64); C = 128; H = 28; inv = 0.125f;   }
    else if (ch < 448) { f = f14 + (ch - 192);C = 256; H = 14; inv = 0.0625f;  }
    else               { f = f7  + (ch - 448);C = 512; H = 7;  inv = 0.03125f; }

    const int p0 = blockIdx.x * PPB;
    const int pend = min(p0 + PPB, n);

    #pragma unroll 2
    for (int p = p0; p < pend; ++p) {
        float* __restrict__ orow = out + (size_t)p * 963;

        const float X = coord[p * 3 + 0];
        const float Y = coord[p * 3 + 1];
        const float Z = coord[p * 3 + 2];

        // one IEEE divide shared by h and w (<=2ulp vs ref's two divides;
        // verified absmax 0.0156 << 0.149 threshold)
        const float rz = 1.0f / (-Z);
        float h = 250.0f * (-Y) * rz + 112.0f;
        float w = 250.0f * X  * rz + 112.0f;
        h = fminf(fmaxf(h, 0.0f), 223.0f);
        w = fminf(fmaxf(w, 0.0f), 223.0f);

        if (t < 240) {
            const float x = h * inv, y = w * inv;
            const float x1 = floorf(x), x2 = ceilf(x);
            const float y1 = floorf(y), y2 = ceilf(y);
            const int xi1 = min(max((int)x1, 0), H - 1);
            const int xi2 = min(max((int)x2, 0), H - 1);
            const int yi1 = min(max((int)y1, 0), H - 1);
            const int yi2 = min(max((int)y2, 0), H - 1);
            const float w11 = (x2 - x) * (y2 - y);
            const float w21 = (x - x1) * (y2 - y);
            const float w12 = (x2 - x) * (y - y1);
            const float w22 = (x - x1) * (y - y1);

            const int r1 = xi1 * H, r2 = xi2 * H;
            const float4 a = *reinterpret_cast<const float4*>(f + (r1 + yi1) * C);
            const float4 b = *reinterpret_cast<const float4*>(f + (r2 + yi1) * C);
            const float4 d = *reinterpret_cast<const float4*>(f + (r1 + yi2) * C);
            const float4 e = *reinterpret_cast<const float4*>(f + (r2 + yi2) * C);

            F4 r;
            r.x = w11 * a.x + w21 * b.x + w12 * d.x + w22 * e.x;
            r.y = w11 * a.y + w21 * b.y + w12 * d.y + w22 * e.y;
            r.z = w11 * a.z + w21 * b.z + w12 * d.z + w22 * e.z;
            r.w = w11 * a.w + w21 * b.w + w12 * d.w + w22 * e.w;
            *reinterpret_cast<F4*>(orow + 3 + ch) = r;
        } else if (t < 243) {
            orow[t - 240] = coord[p * 3 + (t - 240)];
        }
    }
}

extern "C" void kernel_launch(void* const* d_in, const int* in_sizes, int n_in,
                              void* d_out, int out_size, void* d_ws, size_t ws_size,
                              hipStream_t stream) {
    const float* coord = (const float*)d_in[0];
    const float* f56   = (const float*)d_in[1];
    const float* f28   = (const float*)d_in[2];
    const float* f14   = (const float*)d_in[3];
    const float* f7    = (const float*)d_in[4];
    float* out = (float*)d_out;

    int n = in_sizes[0] / 3;  // 131072 points
    int grid = (n + PPB - 1) / PPB;  // 8192 blocks of 16 consecutive points
    GraphProjection_57483842289710_kernel<<<grid, 256, 0, stream>>>(
        coord, f56, f28, f14, f7, out, n);
}